// Round 4
// baseline (1650.442 us; speedup 1.0000x reference)
//
#include <hip/hip_runtime.h>
#include <math.h>

#define BATCH 16
#define NS 2048
#define NT 96
#define DIM 32
#define ROWL 2144   // NS+NT
#define EPSV 1e-30f

struct Seg { int off[3]; float sc[3]; };

// ---------------------------------------------------------------------------
// Pass 0: per-row feature transforms.
// Spatial row i: [ s (32) | n1=tanh(3*W_ss1@s) | n2=tanh(3*W_ss2@s) | q_st | k_ts ]  (160 floats)
// Temporal row j: [ t (32) | q_ts | k_st ]                                            (96 floats)
// ---------------------------------------------------------------------------
__global__ __launch_bounds__(256) void feat_kernel(
    const float* __restrict__ sp, const float* __restrict__ tp,
    const float* __restrict__ Wss1, const float* __restrict__ Wss2,
    const float* __restrict__ Wqst, const float* __restrict__ bqst,
    const float* __restrict__ Wkst, const float* __restrict__ bkst,
    const float* __restrict__ Wqts, const float* __restrict__ bqts,
    const float* __restrict__ Wkts, const float* __restrict__ bkts,
    float* __restrict__ FS, float* __restrict__ FT)
{
  __shared__ float Wl[6*1056];   // 6 matrices, padded [32][33]
  __shared__ float bl[128];
  __shared__ float xl[8][32];
  const int tid = threadIdx.x;
  {
    const float* Ws[6] = {Wss1, Wss2, Wqst, Wkst, Wqts, Wkts};
    #pragma unroll
    for (int m = 0; m < 6; m++){
      const float* W = Ws[m];
      #pragma unroll
      for (int c = 0; c < 4; c++){
        int idx = c*256 + tid;
        Wl[m*1056 + (idx>>5)*33 + (idx&31)] = W[idx];
      }
    }
    if (tid < 32)        bl[tid] = bqst[tid];
    else if (tid < 64)   bl[tid] = bkst[tid-32];
    else if (tid < 96)   bl[tid] = bqts[tid-64];
    else if (tid < 128)  bl[tid] = bkts[tid-96];
  }
  const int rs = tid >> 5;
  const int f  = tid & 31;
  const int row = blockIdx.x*8 + rs;
  const int NROWS = BATCH*NS;
  const int TOT   = NROWS + BATCH*NT;
  const bool valid = row < TOT;
  const bool isS   = row < NROWS;
  if (valid){
    const float* xp = isS ? (sp + (size_t)row*DIM) : (tp + (size_t)(row-NROWS)*DIM);
    xl[rs][f] = xp[f];
  }
  __syncthreads();
  if (!valid) return;

  if (isS){
    float a1=0.f, a2=0.f, aq=0.f, ak=0.f;
    #pragma unroll
    for (int d=0; d<32; d++){
      float xv = xl[rs][d];
      a1 = fmaf(xv, Wl[0*1056 + f*33 + d], a1);
      a2 = fmaf(xv, Wl[1*1056 + f*33 + d], a2);
      aq = fmaf(xv, Wl[2*1056 + f*33 + d], aq);
      ak = fmaf(xv, Wl[5*1056 + f*33 + d], ak);
    }
    float* o = FS + (size_t)row*160;
    o[f]     = xl[rs][f];
    o[32+f]  = tanhf(3.0f*a1);
    o[64+f]  = tanhf(3.0f*a2);
    o[96+f]  = aq + bl[0  + f];   // bq_st
    o[128+f] = ak + bl[96 + f];   // bk_ts
  } else {
    const int rt = row - NROWS;
    float aq=0.f, ak=0.f;
    #pragma unroll
    for (int d=0; d<32; d++){
      float xv = xl[rs][d];
      aq = fmaf(xv, Wl[4*1056 + f*33 + d], aq);
      ak = fmaf(xv, Wl[3*1056 + f*33 + d], ak);
    }
    float* o = FT + (size_t)rt*96;
    o[f]     = xl[rs][f];
    o[32+f]  = aq + bl[64 + f];   // bq_ts
    o[64+f]  = ak + bl[32 + f];   // bk_st
  }
}

// ---------------------------------------------------------------------------
// Pass 1: 128x128-tile fp32 GEMM, 8x8 strided microtile per thread, K staged
// in 32-wide chunks (NK chunks; chunk c = segment c of the Seg descriptor).
// Intensity 2 FLOP/LDS-byte (vs 1 for 4x4) -> VALU ceiling ~67% (~105 TF).
// KP=36-dword rows keep float4 alignment; A-reads (row stride 16 -> 4*ty mod
// 32 spacing) conflict-free, B-reads 2-way (free). Writes raw adjacency into
// out + per-region relu-max via int-bits atomicMax (relu >= 0; the 0xAA ws
// poison is a negative int so any update wins -> no init kernel).
// ---------------------------------------------------------------------------
template<int NK>
__global__ __launch_bounds__(256) void adj_tile(
    const float* __restrict__ Fu, int fustride, int NI, Seg su,
    const float* __restrict__ Fv, int fvstride, int NJ, Seg sv,
    float* __restrict__ out, int i0g, int j0g, float* __restrict__ maxslot)
{
  constexpr int KP = 36;   // dwords per LDS row (144 B, 16B-aligned)
  __shared__ __align__(16) float Ut[128*KP];
  __shared__ __align__(16) float Vt[128*KP];
  __shared__ float red[4];
  const int tid = threadIdx.x;
  const int b   = blockIdx.z;
  const int i0t = blockIdx.y*128;
  const int j0t = blockIdx.x*128;
  const int tx  = tid & 15;    // j rows {tx + 16n}
  const int ty  = tid >> 4;    // i rows {ty + 16m}

  float acc[8][8] = {};

  #pragma unroll
  for (int c = 0; c < NK; ++c){
    const int koff_u = su.off[c]; const float scu = su.sc[c];
    const int koff_v = sv.off[c]; const float scv = sv.sc[c];
    #pragma unroll
    for (int q = 0; q < 4; ++q){
      int idx = q*256 + tid;        // 0..1023
      int row = idx >> 3;
      int k4  = (idx & 7)*4;
      float4 v = make_float4(0.f,0.f,0.f,0.f);
      int gi = i0t + row;
      if (gi < NI) v = *(const float4*)(Fu + (size_t)(b*NI + gi)*fustride + koff_u + k4);
      v.x*=scu; v.y*=scu; v.z*=scu; v.w*=scu;
      *(float4*)&Ut[row*KP + k4] = v;
    }
    #pragma unroll
    for (int q = 0; q < 4; ++q){
      int idx = q*256 + tid;
      int row = idx >> 3;
      int k4  = (idx & 7)*4;
      float4 v = make_float4(0.f,0.f,0.f,0.f);
      int gj = j0t + row;
      if (gj < NJ) v = *(const float4*)(Fv + (size_t)(b*NJ + gj)*fvstride + koff_v + k4);
      v.x*=scv; v.y*=scv; v.z*=scv; v.w*=scv;
      *(float4*)&Vt[row*KP + k4] = v;
    }
    __syncthreads();

    #pragma unroll
    for (int k = 0; k < 32; k += 4){
      float4 a[8], bb[8];
      #pragma unroll
      for (int m=0;m<8;m++) a[m]  = *(const float4*)&Ut[(ty + 16*m)*KP + k];
      #pragma unroll
      for (int n=0;n<8;n++) bb[n] = *(const float4*)&Vt[(tx + 16*n)*KP + k];
      #pragma unroll
      for (int m=0;m<8;m++){
        #pragma unroll
        for (int n=0;n<8;n++){
          acc[m][n] = fmaf(a[m].x, bb[n].x, acc[m][n]);
          acc[m][n] = fmaf(a[m].y, bb[n].y, acc[m][n]);
          acc[m][n] = fmaf(a[m].z, bb[n].z, acc[m][n]);
          acc[m][n] = fmaf(a[m].w, bb[n].w, acc[m][n]);
        }
      }
    }
    __syncthreads();
  }

  float lmax = 0.f;
  const size_t obase = (size_t)b*ROWL*ROWL;
  #pragma unroll
  for (int m=0;m<8;m++){
    int gi = i0t + ty + 16*m;
    if (gi < NI){
      #pragma unroll
      for (int n=0;n<8;n++){
        int gj = j0t + tx + 16*n;
        if (gj < NJ){
          out[obase + (size_t)(i0g+gi)*ROWL + (j0g+gj)] = acc[m][n];
          lmax = fmaxf(lmax, acc[m][n]);
        }
      }
    }
  }
  #pragma unroll
  for (int off = 32; off > 0; off >>= 1)
    lmax = fmaxf(lmax, __shfl_xor(lmax, off));
  if ((tid & 63) == 0) red[tid >> 6] = lmax;
  __syncthreads();
  if (tid == 0){
    float m4 = fmaxf(fmaxf(red[0], red[1]), fmaxf(red[2], red[3]));
    atomicMax((int*)maxslot, __float_as_int(m4));
  }
}

// ---------------------------------------------------------------------------
// Pass 2: out = tanh(relu(out)/(blockmax+eps)); zero strict-lower-tri of tt.
// One block per output row; NS boundary lands at float4-col 512 -> wave-
// uniform region pick. tanh arg in [0,1] -> closed form with __expf is
// exact-range-safe and ~5x cheaper than ocml tanhf.
// ---------------------------------------------------------------------------
__device__ __forceinline__ float tanh01(float x){
  float e = __expf(2.0f*x);
  return __fdividef(e - 1.0f, e + 1.0f);
}
__device__ __forceinline__ float4 uni4(float4 v, float r){
  v.x = tanh01(fmaxf(v.x,0.f)*r);
  v.y = tanh01(fmaxf(v.y,0.f)*r);
  v.z = tanh01(fmaxf(v.z,0.f)*r);
  v.w = tanh01(fmaxf(v.w,0.f)*r);
  return v;
}

__global__ __launch_bounds__(256) void uni_kernel(float* __restrict__ out,
                                                  const float* __restrict__ mx)
{
  const int row = blockIdx.x;          // b*ROWL + i
  const int i   = row % ROWL;
  const bool top = (i < NS);
  const float rl = 1.0f/((top ? mx[0] : mx[2]) + EPSV);   // j <  NS
  const float rr = 1.0f/((top ? mx[1] : mx[3]) + EPSV);   // j >= NS
  float4* rowp = (float4*)(out + (size_t)row*ROWL);
  const int tid = threadIdx.x;

  rowp[tid]       = uni4(rowp[tid],       rl);
  rowp[tid + 256] = uni4(rowp[tid + 256], rl);

  if (tid < 24){
    float4 v = uni4(rowp[tid + 512], rr);
    if (!top){
      int il = i - NS;
      int jl = 4*tid;
      if (jl+0 < il) v.x = 0.f;
      if (jl+1 < il) v.y = 0.f;
      if (jl+2 < il) v.z = 0.f;
      if (jl+3 < il) v.w = 0.f;
    }
    rowp[tid + 512] = v;
  }
}

extern "C" void kernel_launch(void* const* d_in, const int* in_sizes, int n_in,
                              void* d_out, int out_size, void* d_ws, size_t ws_size,
                              hipStream_t stream)
{
  const float* sp   = (const float*)d_in[0];
  const float* tp   = (const float*)d_in[1];
  const float* Wss1 = (const float*)d_in[2];
  const float* Wss2 = (const float*)d_in[3];
  const float* Wqst = (const float*)d_in[4];
  const float* bqst = (const float*)d_in[5];
  const float* Wkst = (const float*)d_in[6];
  const float* bkst = (const float*)d_in[7];
  const float* Wqts = (const float*)d_in[8];
  const float* bqts = (const float*)d_in[9];
  const float* Wkts = (const float*)d_in[10];
  const float* bkts = (const float*)d_in[11];
  float* out  = (float*)d_out;
  float* wsf  = (float*)d_ws;
  float* maxs = wsf;                         // 4 relu-max slots
  float* FS   = wsf + 64;                    // 16*2048*160 floats (~21 MB)
  float* FT   = FS + (size_t)BATCH*NS*160;   // 16*96*96 floats   (~0.6 MB)

  feat_kernel<<<dim3((BATCH*(NS+NT))/8), 256, 0, stream>>>(
      sp,tp,Wss1,Wss2,Wqst,bqst,Wkst,bkst,Wqts,bqts,Wkts,bkts,FS,FT);

  // ss: u=[s, 3*n1, -3*n2], v=[s, n2, n1]  (K=96)
  Seg su_ss = {{0,32,64},{1.f,3.f,-3.f}};
  Seg sv_ss = {{0,64,32},{1.f,1.f,1.f}};
  adj_tile<3><<<dim3(16,16,BATCH), 256, 0, stream>>>(
      FS,160,NS,su_ss, FS,160,NS,sv_ss, out, 0,0, maxs+0);

  // st: u=[s, q_st], v=[t, k_st]  (K=64)
  Seg su_st = {{0,96,0},{1.f,1.f,0.f}};
  Seg sv_st = {{0,64,0},{1.f,1.f,0.f}};
  adj_tile<2><<<dim3(1,16,BATCH), 256, 0, stream>>>(
      FS,160,NS,su_st, FT,96,NT,sv_st, out, 0,NS, maxs+1);

  // ts: u=[t, q_ts], v=[s, k_ts]  (K=64)
  Seg su_ts = {{0,32,0},{1.f,1.f,0.f}};
  Seg sv_ts = {{0,128,0},{1.f,1.f,0.f}};
  adj_tile<2><<<dim3(16,1,BATCH), 256, 0, stream>>>(
      FT,96,NT,su_ts, FS,160,NS,sv_ts, out, NS,0, maxs+2);

  // tt: u=v=[t]  (K=32)
  Seg s_tt = {{0,0,0},{1.f,0.f,0.f}};
  adj_tile<1><<<dim3(1,1,BATCH), 256, 0, stream>>>(
      FT,96,NT,s_tt, FT,96,NT,s_tt, out, NS,NS, maxs+3);

  uni_kernel<<<BATCH*ROWL, 256, 0, stream>>>(out, maxs);
}

// Round 6
// 638.788 us; speedup vs baseline: 2.5837x; 2.5837x over previous
//
#include <hip/hip_runtime.h>
#include <math.h>

#define BATCH 16
#define NS 2048
#define NT 96
#define DIM 32
#define ROWL 2144   // NS+NT
#define EPSV 1e-30f

// Feature-plane layouts (bf16 hi/lo planes, ushort bit patterns):
// spatial row (stride 224): [0:32)=s [32:64)=3*n1 [64:96)=-3*n2 [96:128)=n2
//                           [128:160)=n1 [160:192)=q_st [192:224)=k_ts
// temporal row (stride 96): [0:32)=t [32:64)=q_ts [64:96)=k_st
#define FS_STRIDE 224
#define FT_STRIDE 96

typedef __attribute__((ext_vector_type(8))) short bf16x8;
typedef __attribute__((ext_vector_type(4))) float f32x4;

__device__ __forceinline__ ushort f2bf_rn(float x){
  uint u = __float_as_uint(x);
  return (ushort)((u + 0x7FFFu + ((u >> 16) & 1u)) >> 16);
}
__device__ __forceinline__ float bf2f(ushort h){
  return __uint_as_float(((uint)h) << 16);
}

// ---------------------------------------------------------------------------
// Pass 0: per-row transforms -> bf16 hi/lo feature planes (hi = rn(x),
// lo = rn(x - hi)), so the GEMM kernels can run bf16x3 MFMA (fp32-equivalent:
// dropped lo*lo term ~2^-18 relative).
// ---------------------------------------------------------------------------
__global__ __launch_bounds__(256) void feat_kernel(
    const float* __restrict__ sp, const float* __restrict__ tp,
    const float* __restrict__ Wss1, const float* __restrict__ Wss2,
    const float* __restrict__ Wqst, const float* __restrict__ bqst,
    const float* __restrict__ Wkst, const float* __restrict__ bkst,
    const float* __restrict__ Wqts, const float* __restrict__ bqts,
    const float* __restrict__ Wkts, const float* __restrict__ bkts,
    ushort* __restrict__ FShi, ushort* __restrict__ FSlo,
    ushort* __restrict__ FThi, ushort* __restrict__ FTlo)
{
  __shared__ float Wl[6*1056];   // [32][33]-padded
  __shared__ float bl[128];
  __shared__ float xl[8][32];
  const int tid = threadIdx.x;
  {
    const float* Ws[6] = {Wss1, Wss2, Wqst, Wkst, Wqts, Wkts};
    #pragma unroll
    for (int m = 0; m < 6; m++){
      const float* W = Ws[m];
      #pragma unroll
      for (int c = 0; c < 4; c++){
        int idx = c*256 + tid;
        Wl[m*1056 + (idx>>5)*33 + (idx&31)] = W[idx];
      }
    }
    if (tid < 32)        bl[tid] = bqst[tid];
    else if (tid < 64)   bl[tid] = bkst[tid-32];
    else if (tid < 96)   bl[tid] = bqts[tid-64];
    else if (tid < 128)  bl[tid] = bkts[tid-96];
  }
  const int rs = tid >> 5;
  const int f  = tid & 31;
  const int row = blockIdx.x*8 + rs;
  const int NROWS = BATCH*NS;
  const int TOT   = NROWS + BATCH*NT;
  const bool valid = row < TOT;
  const bool isS   = row < NROWS;
  if (valid){
    const float* xp = isS ? (sp + (size_t)row*DIM) : (tp + (size_t)(row-NROWS)*DIM);
    xl[rs][f] = xp[f];
  }
  __syncthreads();
  if (!valid) return;

  if (isS){
    float a1=0.f, a2=0.f, aq=0.f, ak=0.f;
    #pragma unroll
    for (int d=0; d<32; d++){
      float xv = xl[rs][d];
      a1 = fmaf(xv, Wl[0*1056 + f*33 + d], a1);
      a2 = fmaf(xv, Wl[1*1056 + f*33 + d], a2);
      aq = fmaf(xv, Wl[2*1056 + f*33 + d], aq);
      ak = fmaf(xv, Wl[5*1056 + f*33 + d], ak);
    }
    float n1 = tanhf(3.0f*a1);
    float n2 = tanhf(3.0f*a2);
    float vals[7];
    vals[0] = xl[rs][f];        // s
    vals[1] = 3.0f*n1;          // 3*n1
    vals[2] = -3.0f*n2;         // -3*n2
    vals[3] = n2;
    vals[4] = n1;
    vals[5] = aq + bl[0  + f];  // q_st
    vals[6] = ak + bl[96 + f];  // k_ts
    ushort* oh = FShi + (size_t)row*FS_STRIDE + f;
    ushort* ol = FSlo + (size_t)row*FS_STRIDE + f;
    #pragma unroll
    for (int sgm = 0; sgm < 7; sgm++){
      float x = vals[sgm];
      ushort h = f2bf_rn(x);
      oh[sgm*32] = h;
      ol[sgm*32] = f2bf_rn(x - bf2f(h));
    }
  } else {
    const int rt = row - NROWS;
    float aq=0.f, ak=0.f;
    #pragma unroll
    for (int d=0; d<32; d++){
      float xv = xl[rs][d];
      aq = fmaf(xv, Wl[4*1056 + f*33 + d], aq);
      ak = fmaf(xv, Wl[3*1056 + f*33 + d], ak);
    }
    float vals[3];
    vals[0] = xl[rs][f];        // t
    vals[1] = aq + bl[64 + f];  // q_ts
    vals[2] = ak + bl[32 + f];  // k_st
    ushort* oh = FThi + (size_t)rt*FT_STRIDE + f;
    ushort* ol = FTlo + (size_t)rt*FT_STRIDE + f;
    #pragma unroll
    for (int sgm = 0; sgm < 3; sgm++){
      float x = vals[sgm];
      ushort h = f2bf_rn(x);
      oh[sgm*32] = h;
      ol[sgm*32] = f2bf_rn(x - bf2f(h));
    }
  }
}

// ---------------------------------------------------------------------------
// Pass 1: 64x64-tile bf16x3 MFMA GEMM. 4 waves as 2x2 of 32x32; per 16x16
// output and 32-wide k-block: 3 MFMA (hi*hi, hi*lo, lo*hi) into fp32 acc.
// Both operands row-major K-contiguous ("A*B^T"): identical fragment gather
// (row = lane&15, k = (lane>>4)*8). C/D layout per m89: col=lane&15,
// row=(lane>>4)*4+reg. K staged once in LDS; KP=K+8 pad -> row strides
// 52/36/40 dwords: quarter-wave b128 reads hit all 32 banks with only 2-way
// aliasing (free, m136). Relu-max per region via int-bits atomicMax
// (values >= 0; 0xAA ws poison is a negative int so any update wins).
// Round-4 lesson: fp32 8x8 microtile spilled (VGPR 256, 2.2GB scratch
// writes); this kernel holds ~16 acc + 32 frag VGPRs, no spill.
// ---------------------------------------------------------------------------
template<int K>
__device__ __forceinline__ void stage64(const ushort* __restrict__ src, int stride,
    int nrows, int row0, int o0, int o1, int o2, ushort* __restrict__ dst)
{
  constexpr int CPR = K/8;       // 16B cells per row
  constexpr int KP  = K + 8;
  for (int u = threadIdx.x; u < 64*CPR; u += 256){
    int row  = u / CPR;
    int cell = u - row*CPR;
    int seg  = cell >> 2;
    int ko   = (cell & 3)*8;
    int so   = (seg == 0) ? o0 : ((seg == 1) ? o1 : o2);
    uint4 v = make_uint4(0u,0u,0u,0u);
    int g = row0 + row;
    if (g < nrows) v = *(const uint4*)(src + (size_t)g*stride + so + ko);
    *(uint4*)(dst + row*KP + cell*8) = v;
  }
}

template<int K>
__global__ __launch_bounds__(256) void adj_mfma(
    const ushort* __restrict__ Uhi, const ushort* __restrict__ Ulo, int ustride,
    int NI, int uo0, int uo1, int uo2,
    const ushort* __restrict__ Vhi, const ushort* __restrict__ Vlo, int vstride,
    int NJ, int vo0, int vo1, int vo2,
    float* __restrict__ out, int i0g, int j0g, float* __restrict__ maxslot)
{
  constexpr int KP = K + 8;
  __shared__ __align__(16) ushort sUhi[64*KP];
  __shared__ __align__(16) ushort sUlo[64*KP];
  __shared__ __align__(16) ushort sVhi[64*KP];
  __shared__ __align__(16) ushort sVlo[64*KP];
  __shared__ float red[4];
  const int tid = threadIdx.x;
  const int b   = blockIdx.z;
  const int i0t = blockIdx.y*64;
  const int j0t = blockIdx.x*64;

  stage64<K>(Uhi + (size_t)b*NI*ustride, ustride, NI, i0t, uo0,uo1,uo2, sUhi);
  stage64<K>(Ulo + (size_t)b*NI*ustride, ustride, NI, i0t, uo0,uo1,uo2, sUlo);
  stage64<K>(Vhi + (size_t)b*NJ*vstride, vstride, NJ, j0t, vo0,vo1,vo2, sVhi);
  stage64<K>(Vlo + (size_t)b*NJ*vstride, vstride, NJ, j0t, vo0,vo1,vo2, sVlo);
  __syncthreads();

  const int lane = tid & 63;
  const int w    = tid >> 6;        // wave 0..3
  const int wm   = w >> 1;          // row half
  const int wn   = w & 1;           // col half
  const int l15  = lane & 15;
  const int l4   = lane >> 4;

  f32x4 acc[2][2] = {};

  #pragma unroll
  for (int kb = 0; kb < K/32; ++kb){
    const int kof = kb*32 + l4*8;
    bf16x8 ah0 = *(const bf16x8*)&sUhi[(wm*32 +  0 + l15)*KP + kof];
    bf16x8 ah1 = *(const bf16x8*)&sUhi[(wm*32 + 16 + l15)*KP + kof];
    bf16x8 al0 = *(const bf16x8*)&sUlo[(wm*32 +  0 + l15)*KP + kof];
    bf16x8 al1 = *(const bf16x8*)&sUlo[(wm*32 + 16 + l15)*KP + kof];
    bf16x8 bh0 = *(const bf16x8*)&sVhi[(wn*32 +  0 + l15)*KP + kof];
    bf16x8 bh1 = *(const bf16x8*)&sVhi[(wn*32 + 16 + l15)*KP + kof];
    bf16x8 bl0 = *(const bf16x8*)&sVlo[(wn*32 +  0 + l15)*KP + kof];
    bf16x8 bl1 = *(const bf16x8*)&sVlo[(wn*32 + 16 + l15)*KP + kof];

    acc[0][0] = __builtin_amdgcn_mfma_f32_16x16x32_bf16(ah0, bh0, acc[0][0], 0,0,0);
    acc[0][0] = __builtin_amdgcn_mfma_f32_16x16x32_bf16(ah0, bl0, acc[0][0], 0,0,0);
    acc[0][0] = __builtin_amdgcn_mfma_f32_16x16x32_bf16(al0, bh0, acc[0][0], 0,0,0);

    acc[0][1] = __builtin_amdgcn_mfma_f32_16x16x32_bf16(ah0, bh1, acc[0][1], 0,0,0);
    acc[0][1] = __builtin_amdgcn_mfma_f32_16x16x32_bf16(ah0, bl1, acc[0][1], 0,0,0);
    acc[0][1] = __builtin_amdgcn_mfma_f32_16x16x32_bf16(al0, bh1, acc[0][1], 0,0,0);

    acc[1][0] = __builtin_amdgcn_mfma_f32_16x16x32_bf16(ah1, bh0, acc[1][0], 0,0,0);
    acc[1][0] = __builtin_amdgcn_mfma_f32_16x16x32_bf16(ah1, bl0, acc[1][0], 0,0,0);
    acc[1][0] = __builtin_amdgcn_mfma_f32_16x16x32_bf16(al1, bh0, acc[1][0], 0,0,0);

    acc[1][1] = __builtin_amdgcn_mfma_f32_16x16x32_bf16(ah1, bh1, acc[1][1], 0,0,0);
    acc[1][1] = __builtin_amdgcn_mfma_f32_16x16x32_bf16(ah1, bl1, acc[1][1], 0,0,0);
    acc[1][1] = __builtin_amdgcn_mfma_f32_16x16x32_bf16(al1, bh1, acc[1][1], 0,0,0);
  }

  float lmax = 0.f;
  const size_t obase = (size_t)b*ROWL*ROWL;
  #pragma unroll
  for (int sm = 0; sm < 2; sm++){
    #pragma unroll
    for (int sn = 0; sn < 2; sn++){
      #pragma unroll
      for (int r = 0; r < 4; r++){
        int gi = i0t + wm*32 + sm*16 + l4*4 + r;
        int gj = j0t + wn*32 + sn*16 + l15;
        if (gi < NI && gj < NJ){
          float v = acc[sm][sn][r];
          out[obase + (size_t)(i0g+gi)*ROWL + (j0g+gj)] = v;
          lmax = fmaxf(lmax, v);
        }
      }
    }
  }
  #pragma unroll
  for (int off = 32; off > 0; off >>= 1)
    lmax = fmaxf(lmax, __shfl_xor(lmax, off));
  if ((tid & 63) == 0) red[tid >> 6] = lmax;
  __syncthreads();
  if (tid == 0){
    float m4 = fmaxf(fmaxf(red[0], red[1]), fmaxf(red[2], red[3]));
    atomicMax((int*)maxslot, __float_as_int(m4));
  }
}

// ---------------------------------------------------------------------------
// Pass 2: out = tanh(relu(out)/(blockmax+eps)); zero strict-lower-tri of tt.
// Block-per-row; NS boundary at float4-col 512 -> wave-uniform region pick.
// tanh arg in [0,1] -> closed form with __expf, exact-range-safe.
// ---------------------------------------------------------------------------
__device__ __forceinline__ float tanh01(float x){
  float e = __expf(2.0f*x);
  return __fdividef(e - 1.0f, e + 1.0f);
}
__device__ __forceinline__ float4 uni4(float4 v, float r){
  v.x = tanh01(fmaxf(v.x,0.f)*r);
  v.y = tanh01(fmaxf(v.y,0.f)*r);
  v.z = tanh01(fmaxf(v.z,0.f)*r);
  v.w = tanh01(fmaxf(v.w,0.f)*r);
  return v;
}

__global__ __launch_bounds__(256) void uni_kernel(float* __restrict__ out,
                                                  const float* __restrict__ mx)
{
  const int row = blockIdx.x;          // b*ROWL + i
  const int i   = row % ROWL;
  const bool top = (i < NS);
  const float rl = 1.0f/((top ? mx[0] : mx[2]) + EPSV);   // j <  NS
  const float rr = 1.0f/((top ? mx[1] : mx[3]) + EPSV);   // j >= NS
  float4* rowp = (float4*)(out + (size_t)row*ROWL);
  const int tid = threadIdx.x;

  rowp[tid]       = uni4(rowp[tid],       rl);
  rowp[tid + 256] = uni4(rowp[tid + 256], rl);

  if (tid < 24){
    float4 v = uni4(rowp[tid + 512], rr);
    if (!top){
      int il = i - NS;
      int jl = 4*tid;
      if (jl+0 < il) v.x = 0.f;
      if (jl+1 < il) v.y = 0.f;
      if (jl+2 < il) v.z = 0.f;
      if (jl+3 < il) v.w = 0.f;
    }
    rowp[tid + 512] = v;
  }
}

extern "C" void kernel_launch(void* const* d_in, const int* in_sizes, int n_in,
                              void* d_out, int out_size, void* d_ws, size_t ws_size,
                              hipStream_t stream)
{
  const float* sp   = (const float*)d_in[0];
  const float* tp   = (const float*)d_in[1];
  const float* Wss1 = (const float*)d_in[2];
  const float* Wss2 = (const float*)d_in[3];
  const float* Wqst = (const float*)d_in[4];
  const float* bqst = (const float*)d_in[5];
  const float* Wkst = (const float*)d_in[6];
  const float* bkst = (const float*)d_in[7];
  const float* Wqts = (const float*)d_in[8];
  const float* bqts = (const float*)d_in[9];
  const float* Wkts = (const float*)d_in[10];
  const float* bkts = (const float*)d_in[11];
  float* out  = (float*)d_out;
  float* wsf  = (float*)d_ws;
  float* maxs = wsf;                              // 4 relu-max slots

  const size_t SHROWS = (size_t)BATCH*NS;         // 32768
  const size_t STROWS = (size_t)BATCH*NT;         // 1536
  ushort* FShi = (ushort*)(wsf + 16);             // 64B-aligned
  ushort* FSlo = FShi + SHROWS*FS_STRIDE;
  ushort* FThi = FSlo + SHROWS*FS_STRIDE;
  ushort* FTlo = FThi + STROWS*FT_STRIDE;         // total ~30 MB

  feat_kernel<<<dim3((BATCH*(NS+NT))/8), 256, 0, stream>>>(
      sp,tp,Wss1,Wss2,Wqst,bqst,Wkst,bkst,Wqts,bqts,Wkts,bkts,
      FShi,FSlo,FThi,FTlo);

  // ss: U=[s,3n1,-3n2] offs {0,32,64}; V=[s,n2,n1] offs {0,96,128}; K=96
  adj_mfma<96><<<dim3(32,32,BATCH), 256, 0, stream>>>(
      FShi,FSlo,FS_STRIDE,NS, 0,32,64,
      FShi,FSlo,FS_STRIDE,NS, 0,96,128,
      out, 0,0, maxs+0);

  // st: U=[s,q_st] offs {0,160}; V=[t,k_st] offs {0,64}; K=64
  adj_mfma<64><<<dim3(2,32,BATCH), 256, 0, stream>>>(
      FShi,FSlo,FS_STRIDE,NS, 0,160,0,
      FThi,FTlo,FT_STRIDE,NT, 0,64,0,
      out, 0,NS, maxs+1);

  // ts: U=[t,q_ts] offs {0,32}; V=[s,k_ts] offs {0,192}; K=64
  adj_mfma<64><<<dim3(32,2,BATCH), 256, 0, stream>>>(
      FThi,FTlo,FT_STRIDE,NT, 0,32,0,
      FShi,FSlo,FS_STRIDE,NS, 0,192,0,
      out, NS,0, maxs+2);

  // tt: U=V=[t] off {0}; K=32
  adj_mfma<32><<<dim3(2,2,BATCH), 256, 0, stream>>>(
      FThi,FTlo,FT_STRIDE,NT, 0,0,0,
      FThi,FTlo,FT_STRIDE,NT, 0,0,0,
      out, NS,NS, maxs+3);

  uni_kernel<<<BATCH*ROWL, 256, 0, stream>>>(out, maxs);
}

// Round 7
// 548.718 us; speedup vs baseline: 3.0078x; 1.1641x over previous
//
#include <hip/hip_runtime.h>
#include <math.h>

#define BATCH 16
#define NS 2048
#define NT 96
#define DIM 32
#define ROWL 2144   // NS+NT
#define EPSV 1e-30f

// Feature-plane layouts (bf16 hi/lo planes, ushort bit patterns):
// spatial row (stride 224): [0:32)=s [32:64)=3*n1 [64:96)=-3*n2 [96:128)=n2
//                           [128:160)=n1 [160:192)=q_st [192:224)=k_ts
// temporal row (stride 96): [0:32)=t [32:64)=q_ts [64:96)=k_st
#define FS_STRIDE 224
#define FT_STRIDE 96

typedef __attribute__((ext_vector_type(8))) short bf16x8;
typedef __attribute__((ext_vector_type(4))) float f32x4;

__device__ __forceinline__ ushort f2bf_rn(float x){
  uint u = __float_as_uint(x);
  return (ushort)((u + 0x7FFFu + ((u >> 16) & 1u)) >> 16);
}
__device__ __forceinline__ float bf2f(ushort h){
  return __uint_as_float(((uint)h) << 16);
}

// ---------------------------------------------------------------------------
// Pass 0: per-row transforms -> bf16 hi/lo feature planes (hi = rn(x),
// lo = rn(x - hi)) for bf16x3 MFMA (fp32-equivalent; drops only lo*lo).
// ---------------------------------------------------------------------------
__global__ __launch_bounds__(256) void feat_kernel(
    const float* __restrict__ sp, const float* __restrict__ tp,
    const float* __restrict__ Wss1, const float* __restrict__ Wss2,
    const float* __restrict__ Wqst, const float* __restrict__ bqst,
    const float* __restrict__ Wkst, const float* __restrict__ bkst,
    const float* __restrict__ Wqts, const float* __restrict__ bqts,
    const float* __restrict__ Wkts, const float* __restrict__ bkts,
    ushort* __restrict__ FShi, ushort* __restrict__ FSlo,
    ushort* __restrict__ FThi, ushort* __restrict__ FTlo)
{
  __shared__ float Wl[6*1056];   // [32][33]-padded
  __shared__ float bl[128];
  __shared__ float xl[8][32];
  const int tid = threadIdx.x;
  {
    const float* Ws[6] = {Wss1, Wss2, Wqst, Wkst, Wqts, Wkts};
    #pragma unroll
    for (int m = 0; m < 6; m++){
      const float* W = Ws[m];
      #pragma unroll
      for (int c = 0; c < 4; c++){
        int idx = c*256 + tid;
        Wl[m*1056 + (idx>>5)*33 + (idx&31)] = W[idx];
      }
    }
    if (tid < 32)        bl[tid] = bqst[tid];
    else if (tid < 64)   bl[tid] = bkst[tid-32];
    else if (tid < 96)   bl[tid] = bqts[tid-64];
    else if (tid < 128)  bl[tid] = bkts[tid-96];
  }
  const int rs = tid >> 5;
  const int f  = tid & 31;
  const int row = blockIdx.x*8 + rs;
  const int NROWS = BATCH*NS;
  const int TOT   = NROWS + BATCH*NT;
  const bool valid = row < TOT;
  const bool isS   = row < NROWS;
  if (valid){
    const float* xp = isS ? (sp + (size_t)row*DIM) : (tp + (size_t)(row-NROWS)*DIM);
    xl[rs][f] = xp[f];
  }
  __syncthreads();
  if (!valid) return;

  if (isS){
    float a1=0.f, a2=0.f, aq=0.f, ak=0.f;
    #pragma unroll
    for (int d=0; d<32; d++){
      float xv = xl[rs][d];
      a1 = fmaf(xv, Wl[0*1056 + f*33 + d], a1);
      a2 = fmaf(xv, Wl[1*1056 + f*33 + d], a2);
      aq = fmaf(xv, Wl[2*1056 + f*33 + d], aq);
      ak = fmaf(xv, Wl[5*1056 + f*33 + d], ak);
    }
    float n1 = tanhf(3.0f*a1);
    float n2 = tanhf(3.0f*a2);
    float vals[7];
    vals[0] = xl[rs][f];        // s
    vals[1] = 3.0f*n1;          // 3*n1
    vals[2] = -3.0f*n2;         // -3*n2
    vals[3] = n2;
    vals[4] = n1;
    vals[5] = aq + bl[0  + f];  // q_st
    vals[6] = ak + bl[96 + f];  // k_ts
    ushort* oh = FShi + (size_t)row*FS_STRIDE + f;
    ushort* ol = FSlo + (size_t)row*FS_STRIDE + f;
    #pragma unroll
    for (int sgm = 0; sgm < 7; sgm++){
      float x = vals[sgm];
      ushort h = f2bf_rn(x);
      oh[sgm*32] = h;
      ol[sgm*32] = f2bf_rn(x - bf2f(h));
    }
  } else {
    const int rt = row - NROWS;
    float aq=0.f, ak=0.f;
    #pragma unroll
    for (int d=0; d<32; d++){
      float xv = xl[rs][d];
      aq = fmaf(xv, Wl[4*1056 + f*33 + d], aq);
      ak = fmaf(xv, Wl[3*1056 + f*33 + d], ak);
    }
    float vals[3];
    vals[0] = xl[rs][f];        // t
    vals[1] = aq + bl[64 + f];  // q_ts
    vals[2] = ak + bl[32 + f];  // k_st
    ushort* oh = FThi + (size_t)rt*FT_STRIDE + f;
    ushort* ol = FTlo + (size_t)rt*FT_STRIDE + f;
    #pragma unroll
    for (int sgm = 0; sgm < 3; sgm++){
      float x = vals[sgm];
      ushort h = f2bf_rn(x);
      oh[sgm*32] = h;
      ol[sgm*32] = f2bf_rn(x - bf2f(h));
    }
  }
}

// ---------------------------------------------------------------------------
// Pass 1: 64(i) x 128(j) tile, bf16x3 MFMA, FRAGMENT-ORDER LDS.
// Round-6 lesson: row-major LDS + b128 fragment reads = 8-way bank conflict
// (row stride always 0 mod 4 dwords; each b128 phase hits only 8 banks;
// 8.4M conflicts, MfmaUtil 7.4%). Fix: store each 16B fragment cell at
// cell#((g*NKB+kb)*4+q)*16+r15 so a wave's fragment read is base+lane*16B --
// linear 1KB, conflict-free by construction; staging writes are a permutation
// of a linear 1KB window per wave (free).
// 4 waves as 2(row)x2(col); wave owns 32x64 = 2 rowgroups x 4 colgroups;
// per 32-k block: 12 b128 reads -> 24 MFMAs (vs 8->12 before).
// Single stage + single barrier (whole K resident; 72KB LDS @K=96 -> 2
// blocks/CU). Relu-max per region via int-bits atomicMax (relu >= 0; 0xAA ws
// poison is a negative int so any update wins -> no init kernel).
// ---------------------------------------------------------------------------
template<int NKB>   // K = NKB*32
__global__ __launch_bounds__(256, 2) void adj_mfma(
    const ushort* __restrict__ Uhi, const ushort* __restrict__ Ulo, int ustride,
    int NI, int uo0, int uo1, int uo2,
    const ushort* __restrict__ Vhi, const ushort* __restrict__ Vlo, int vstride,
    int NJ, int vo0, int vo1, int vo2,
    float* __restrict__ out, int i0g, int j0g, float* __restrict__ maxslot)
{
  constexpr int ACELLS = 4*NKB*64;   // 4 rowgroups  * NKB * 4q * 16r   (16B cells)
  constexpr int BCELLS = 8*NKB*64;   // 8 colgroups  * NKB * 4q * 16r
  __shared__ __align__(16) ushort sAh[ACELLS*8];
  __shared__ __align__(16) ushort sAl[ACELLS*8];
  __shared__ __align__(16) ushort sBh[BCELLS*8];
  __shared__ __align__(16) ushort sBl[BCELLS*8];
  __shared__ float red[4];
  const int tid = threadIdx.x;
  const int b   = blockIdx.z;
  const int i0t = blockIdx.y*64;
  const int j0t = blockIdx.x*128;

  const ushort* Ubh = Uhi + (size_t)b*NI*ustride;
  const ushort* Ubl = Ulo + (size_t)b*NI*ustride;
  const ushort* Vbh = Vhi + (size_t)b*NJ*vstride;
  const ushort* Vbl = Vlo + (size_t)b*NJ*vstride;

  // ---- stage A (64 rows) ----
  for (int u = tid; u < ACELLS; u += 256){
    int q   = u & 3;
    int t   = u >> 2;
    int r15 = t & 15;
    int t2  = t >> 4;            // g*NKB + kb
    int kb  = t2 % NKB;
    int g   = t2 / NKB;
    int so  = (kb == 0) ? uo0 : ((kb == 1) ? uo1 : uo2);
    int gr  = i0t + g*16 + r15;
    uint4 vh = make_uint4(0u,0u,0u,0u), vl = vh;
    if (gr < NI){
      const size_t base = (size_t)gr*ustride + so + q*8;
      vh = *(const uint4*)(Ubh + base);
      vl = *(const uint4*)(Ubl + base);
    }
    int dcell = (t2*4 + q)*16 + r15;
    *(uint4*)&sAh[dcell*8] = vh;
    *(uint4*)&sAl[dcell*8] = vl;
  }
  // ---- stage B (128 cols) ----
  for (int u = tid; u < BCELLS; u += 256){
    int q   = u & 3;
    int t   = u >> 2;
    int r15 = t & 15;
    int t2  = t >> 4;            // g*NKB + kb
    int kb  = t2 % NKB;
    int g   = t2 / NKB;
    int so  = (kb == 0) ? vo0 : ((kb == 1) ? vo1 : vo2);
    int gr  = j0t + g*16 + r15;
    uint4 vh = make_uint4(0u,0u,0u,0u), vl = vh;
    if (gr < NJ){
      const size_t base = (size_t)gr*vstride + so + q*8;
      vh = *(const uint4*)(Vbh + base);
      vl = *(const uint4*)(Vbl + base);
    }
    int dcell = (t2*4 + q)*16 + r15;
    *(uint4*)&sBh[dcell*8] = vh;
    *(uint4*)&sBl[dcell*8] = vl;
  }
  __syncthreads();

  const int lane = tid & 63;
  const int w    = tid >> 6;
  const int wm   = w & 1;          // row half (32 rows)
  const int wn   = w >> 1;         // col half (64 cols)
  const int l15  = lane & 15;
  const int l4   = lane >> 4;

  f32x4 acc[2][4] = {};

  #pragma unroll
  for (int kb = 0; kb < NKB; ++kb){
    bf16x8 ah[2], al[2], bh[4], bl[4];
    #pragma unroll
    for (int m = 0; m < 2; m++){
      int off = ((2*wm + m)*NKB + kb)*512 + lane*8;
      ah[m] = *(const bf16x8*)&sAh[off];
      al[m] = *(const bf16x8*)&sAl[off];
    }
    #pragma unroll
    for (int n = 0; n < 4; n++){
      int off = ((4*wn + n)*NKB + kb)*512 + lane*8;
      bh[n] = *(const bf16x8*)&sBh[off];
      bl[n] = *(const bf16x8*)&sBl[off];
    }
    #pragma unroll
    for (int m = 0; m < 2; m++){
      #pragma unroll
      for (int n = 0; n < 4; n++){
        acc[m][n] = __builtin_amdgcn_mfma_f32_16x16x32_bf16(ah[m], bh[n], acc[m][n], 0,0,0);
        acc[m][n] = __builtin_amdgcn_mfma_f32_16x16x32_bf16(ah[m], bl[n], acc[m][n], 0,0,0);
        acc[m][n] = __builtin_amdgcn_mfma_f32_16x16x32_bf16(al[m], bh[n], acc[m][n], 0,0,0);
      }
    }
  }

  // ---- epilogue: store raw adjacency + per-region relu-max ----
  float lmax = 0.f;
  const size_t obase = (size_t)b*ROWL*ROWL;
  #pragma unroll
  for (int m = 0; m < 2; m++){
    int gi_base = i0t + wm*32 + m*16 + l4*4;
    #pragma unroll
    for (int r = 0; r < 4; r++){
      int gi = gi_base + r;
      if (gi < NI){
        const size_t rowb = obase + (size_t)(i0g+gi)*ROWL + j0g;
        #pragma unroll
        for (int n = 0; n < 4; n++){
          int gj = j0t + wn*64 + n*16 + l15;
          if (gj < NJ){
            float v = acc[m][n][r];
            out[rowb + gj] = v;
            lmax = fmaxf(lmax, v);
          }
        }
      }
    }
  }
  #pragma unroll
  for (int off = 32; off > 0; off >>= 1)
    lmax = fmaxf(lmax, __shfl_xor(lmax, off));
  if ((tid & 63) == 0) red[tid >> 6] = lmax;
  __syncthreads();
  if (tid == 0){
    float m4 = fmaxf(fmaxf(red[0], red[1]), fmaxf(red[2], red[3]));
    atomicMax((int*)maxslot, __float_as_int(m4));
  }
}

// ---------------------------------------------------------------------------
// Pass 2: out = tanh(relu(out)/(blockmax+eps)); zero strict-lower-tri of tt.
// Block-per-row; NS boundary at float4-col 512 -> wave-uniform region pick.
// tanh arg in [0,1] -> closed form with __expf, exact-range-safe.
// ---------------------------------------------------------------------------
__device__ __forceinline__ float tanh01(float x){
  float e = __expf(2.0f*x);
  return __fdividef(e - 1.0f, e + 1.0f);
}
__device__ __forceinline__ float4 uni4(float4 v, float r){
  v.x = tanh01(fmaxf(v.x,0.f)*r);
  v.y = tanh01(fmaxf(v.y,0.f)*r);
  v.z = tanh01(fmaxf(v.z,0.f)*r);
  v.w = tanh01(fmaxf(v.w,0.f)*r);
  return v;
}

__global__ __launch_bounds__(256) void uni_kernel(float* __restrict__ out,
                                                  const float* __restrict__ mx)
{
  const int row = blockIdx.x;          // b*ROWL + i
  const int i   = row % ROWL;
  const bool top = (i < NS);
  const float rl = 1.0f/((top ? mx[0] : mx[2]) + EPSV);   // j <  NS
  const float rr = 1.0f/((top ? mx[1] : mx[3]) + EPSV);   // j >= NS
  float4* rowp = (float4*)(out + (size_t)row*ROWL);
  const int tid = threadIdx.x;

  rowp[tid]       = uni4(rowp[tid],       rl);
  rowp[tid + 256] = uni4(rowp[tid + 256], rl);

  if (tid < 24){
    float4 v = uni4(rowp[tid + 512], rr);
    if (!top){
      int il = i - NS;
      int jl = 4*tid;
      if (jl+0 < il) v.x = 0.f;
      if (jl+1 < il) v.y = 0.f;
      if (jl+2 < il) v.z = 0.f;
      if (jl+3 < il) v.w = 0.f;
    }
    rowp[tid + 512] = v;
  }
}

extern "C" void kernel_launch(void* const* d_in, const int* in_sizes, int n_in,
                              void* d_out, int out_size, void* d_ws, size_t ws_size,
                              hipStream_t stream)
{
  const float* sp   = (const float*)d_in[0];
  const float* tp   = (const float*)d_in[1];
  const float* Wss1 = (const float*)d_in[2];
  const float* Wss2 = (const float*)d_in[3];
  const float* Wqst = (const float*)d_in[4];
  const float* bqst = (const float*)d_in[5];
  const float* Wkst = (const float*)d_in[6];
  const float* bkst = (const float*)d_in[7];
  const float* Wqts = (const float*)d_in[8];
  const float* bqts = (const float*)d_in[9];
  const float* Wkts = (const float*)d_in[10];
  const float* bkts = (const float*)d_in[11];
  float* out  = (float*)d_out;
  float* wsf  = (float*)d_ws;
  float* maxs = wsf;                              // 4 relu-max slots

  const size_t SHROWS = (size_t)BATCH*NS;         // 32768
  const size_t STROWS = (size_t)BATCH*NT;         // 1536
  ushort* FShi = (ushort*)(wsf + 16);             // 64B-aligned
  ushort* FSlo = FShi + SHROWS*FS_STRIDE;
  ushort* FThi = FSlo + SHROWS*FS_STRIDE;
  ushort* FTlo = FThi + STROWS*FT_STRIDE;         // total ~30 MB

  feat_kernel<<<dim3((BATCH*(NS+NT))/8), 256, 0, stream>>>(
      sp,tp,Wss1,Wss2,Wqst,bqst,Wkst,bkst,Wqts,bqts,Wkts,bkts,
      FShi,FSlo,FThi,FTlo);

  // ss: U=[s,3n1,-3n2] offs {0,32,64}; V=[s,n2,n1] offs {0,96,128}; K=96
  adj_mfma<3><<<dim3(16,32,BATCH), 256, 0, stream>>>(
      FShi,FSlo,FS_STRIDE,NS, 0,32,64,
      FShi,FSlo,FS_STRIDE,NS, 0,96,128,
      out, 0,0, maxs+0);

  // st: U=[s,q_st] offs {0,160}; V=[t,k_st] offs {0,64}; K=64
  adj_mfma<2><<<dim3(1,32,BATCH), 256, 0, stream>>>(
      FShi,FSlo,FS_STRIDE,NS, 0,160,0,
      FThi,FTlo,FT_STRIDE,NT, 0,64,0,
      out, 0,NS, maxs+1);

  // ts: U=[t,q_ts] offs {0,32}; V=[s,k_ts] offs {0,192}; K=64
  adj_mfma<2><<<dim3(16,2,BATCH), 256, 0, stream>>>(
      FThi,FTlo,FT_STRIDE,NT, 0,32,0,
      FShi,FSlo,FS_STRIDE,NS, 0,192,0,
      out, NS,0, maxs+2);

  // tt: U=V=[t] off {0}; K=32
  adj_mfma<1><<<dim3(1,2,BATCH), 256, 0, stream>>>(
      FThi,FTlo,FT_STRIDE,NT, 0,0,0,
      FThi,FTlo,FT_STRIDE,NT, 0,0,0,
      out, NS,NS, maxs+3);

  uni_kernel<<<BATCH*ROWL, 256, 0, stream>>>(out, maxs);
}